// Round 19
// baseline (63.722 us; speedup 1.0000x reference)
//
#include <hip/hip_runtime.h>

#define KC   21      // num classes
#define BB   8       // batch
#define CC   256     // feat channels
#define HWP  65536   // 256*256 output pixels per image
#define SRC  4096    // 64*64 source pixels
#define NS2  32      // s-chunks of 128 p (2 source rows each)

// d_ws layout: L bytes [0, 524288) | partialw f32 @ float idx 131072 (5376) |
// partial f32 @ float idx 139264 ([B][NS2][K][C] = 1376256 floats). Disjoint.
#define WSF_PARTW 131072
#define WSF_PART  139264

// ---- k1: per-pixel argmax + gt-match -> label map (proven body, pure) -------
__global__ __launch_bounds__(256, 2)
void k1_classify(const float* __restrict__ preds,
                 const int*   __restrict__ masks,
                 unsigned char* __restrict__ L)
{
    int tid = threadIdx.x;
    int idx = blockIdx.x * 256 + tid;            // over B*HWP/4 = 131072
    int b   = idx >> 14;
    int hw4 = (idx & 16383) << 2;

    const float* pb = preds + (size_t)b * KC * HWP + hw4;
    float va[4][KC];
#pragma unroll
    for (int k = 0; k < KC; ++k) {
        float4 t = *reinterpret_cast<const float4*>(pb + (size_t)k * HWP);
        va[0][k] = t.x; va[1][k] = t.y; va[2][k] = t.z; va[3][k] = t.w;
    }
    int4 mm = *reinterpret_cast<const int4*>(masks + b * HWP + hw4);
    int mk[4] = { mm.x, mm.y, mm.z, mm.w };

    uchar4 r;
    unsigned char* rp = reinterpret_cast<unsigned char*>(&r);
#pragma unroll
    for (int j = 0; j < 4; ++j) {
        float best = va[j][0];
        int   bi   = 0;
#pragma unroll
        for (int k = 1; k < KC; ++k)
            if (va[j][k] > best) { best = va[j][k]; bi = k; }  // first-index ties
        rp[j] = (mk[j] == bi) ? (unsigned char)bi : (unsigned char)255;
    }
    *reinterpret_cast<uchar4*>(L + (size_t)b * HWP + hw4) = r;
}

// ---- k2: gather W for 2 source rows + register-accumulated contraction ------
// Block (s,b): source rows {2s, 2s+1} = 128 p. Gather over hi-res rows
// [8s-2, 8s+9] x 256 cols into ws[21][128] (LDS atomics, dyadic-exact ->
// order-independent). Then thread=channel: acc[21] over all 128 p in regs
// (4 sub-chunks of 32), ONE coalesced store per k. partial: 5.5 MB (was 22).
__global__ __launch_bounds__(256)
void k2_contract(const float* __restrict__ feats,      // [B][C][SRC]
                 const unsigned char* __restrict__ L,  // [B][256][256]
                 float* __restrict__ partial,          // [B][NS2][K][C]
                 float* __restrict__ partialw)         // [B][NS2][K]
{
    __shared__ float ws[KC * 128];    // 10.5 KB
    int s = blockIdx.x, b = blockIdx.y;
    int tid = threadIdx.x;
    int p0 = s * 128;
    int ybase = 2 * s;

    for (int t = tid; t < KC * 32; t += 256)   // zero 672 float4
        *reinterpret_cast<float4*>(ws + t * 4) = make_float4(0.f, 0.f, 0.f, 0.f);
    __syncthreads();

    // gather: 12 hi-res rows x 256 cols (full width -> no col clipping)
    {
        int r4 = tid >> 6, cb = tid & 63;
#pragma unroll
        for (int rr = 0; rr < 3; ++rr) {
            int h = 8 * s - 2 + rr * 4 + r4;
            if ((unsigned)h < 256u) {
                float sy = h * 0.25f - 0.375f;
                int   yt = (int)floorf(sy);
                float wy = sy - (float)yt;
                int ya = yt < 0 ? 0 : yt;
                int yb = yt + 1 > 63 ? 63 : yt + 1;
                float wyy0 = ((ya == ybase)     ? (1.f - wy) : 0.f) + ((yb == ybase)     ? wy : 0.f);
                float wyy1 = ((ya == ybase + 1) ? (1.f - wy) : 0.f) + ((yb == ybase + 1) ? wy : 0.f);
                if (wyy0 != 0.f || wyy1 != 0.f) {
                    const unsigned char* Lrow = L + ((size_t)b << 16) + ((size_t)h << 8);
#pragma unroll
                    for (int j = 0; j < 4; ++j) {
                        int w = cb + j * 64;
                        int k = Lrow[w];
                        if (k < KC) {
                            float sx = w * 0.25f - 0.375f;
                            int   xt = (int)floorf(sx);
                            float wx = sx - (float)xt;
                            int xa = xt < 0 ? 0 : xt;
                            int xb = xt + 1 > 63 ? 63 : xt + 1;
                            float* wk = ws + k * 128;
                            if (wyy0 != 0.f) {                       // row y=2s
                                atomicAdd(wk + xa, wyy0 * (1.f - wx));   // dyadic-exact
                                atomicAdd(wk + xb, wyy0 * wx);
                            }
                            if (wyy1 != 0.f) {                       // row y=2s+1
                                atomicAdd(wk + 64 + xa, wyy1 * (1.f - wx));
                                atomicAdd(wk + 64 + xb, wyy1 * wx);
                            }
                        }
                    }
                }
            }
        }
    }
    __syncthreads();

    // exact per-chunk class-count (rotated reads to spread banks)
    float swcnt = 0.f;
    if (tid < KC) {
#pragma unroll
        for (int i = 0; i < 128; ++i)
            swcnt += ws[tid * 128 + ((i + tid * 8) & 127)];
    }

    // contraction: thread = channel; acc[21] across all 128 p
    float acc[KC];
#pragma unroll
    for (int k = 0; k < KC; ++k) acc[k] = 0.f;

    const float* frow = feats + (size_t)(b * CC + tid) * SRC + p0;
#pragma unroll
    for (int ss = 0; ss < 4; ++ss) {
        float f[32];
#pragma unroll
        for (int q = 0; q < 8; ++q) {
            float4 t = *reinterpret_cast<const float4*>(frow + ss * 32 + q * 4);
            f[q * 4 + 0] = t.x; f[q * 4 + 1] = t.y;
            f[q * 4 + 2] = t.z; f[q * 4 + 3] = t.w;
        }
#pragma unroll
        for (int k = 0; k < KC; ++k) {
            const float* wk = ws + k * 128 + ss * 32;
            float a0 = 0.f, a1 = 0.f, a2 = 0.f, a3 = 0.f;
#pragma unroll
            for (int q = 0; q < 8; ++q) {
                float4 w4 = *reinterpret_cast<const float4*>(wk + q * 4);  // uniform b128
                a0 += w4.x * f[q * 4 + 0];
                a1 += w4.y * f[q * 4 + 1];
                a2 += w4.z * f[q * 4 + 2];
                a3 += w4.w * f[q * 4 + 3];
            }
            acc[k] += (a0 + a1) + (a2 + a3);
        }
    }

    float* op = partial + ((size_t)(b * NS2 + s) * KC) * CC + tid;
#pragma unroll
    for (int k = 0; k < KC; ++k)
        op[(size_t)k * CC] = acc[k];             // coalesced 1KB store per k

    if (tid < KC)
        partialw[(b * NS2 + s) * KC + tid] = swcnt;   // dyadic-exact
}

// ---- k3: reduce s-chunks + batch, normalize, single write (no atomics) ------
__global__ __launch_bounds__(256)
void k3_finalize(const float* __restrict__ partial,   // [B][NS2][K][C]
                 const float* __restrict__ partialw,  // [B][NS2][K]
                 float* __restrict__ out)             // [K][C]
{
    int k = blockIdx.x;    // 21
    int c = threadIdx.x;   // 256

    float r = 0.f;
#pragma unroll 1
    for (int b = 0; b < BB; ++b) {
        float cnt = 0.f;
#pragma unroll
        for (int s = 0; s < NS2; ++s)            // uniform scalar loads
            cnt += partialw[(b * NS2 + s) * KC + k];

        float acc = 0.f;
        const float* base = partial + ((size_t)(b * NS2) * KC + k) * CC + c;
#pragma unroll 8
        for (int s = 0; s < NS2; ++s) acc += base[(size_t)s * KC * CC];

        r += acc / (cnt + 1e-6f);
    }
    out[k * CC + c] = r * 0.125f;                // written once, deterministic
}

extern "C" void kernel_launch(void* const* d_in, const int* in_sizes, int n_in,
                              void* d_out, int out_size, void* d_ws, size_t ws_size,
                              hipStream_t stream) {
    const float* feats = (const float*)d_in[0];   // [8,256,64,64]
    const float* preds = (const float*)d_in[1];   // [8,21,256,256]
    const int*   masks = (const int*)  d_in[2];   // [8,256,256]
    float* out = (float*)d_out;                   // [21,256]

    float* wsf = (float*)d_ws;
    unsigned char* L = (unsigned char*)d_ws;      // 512 KB, fully written by k1
    float* partialw = wsf + WSF_PARTW;
    float* partial  = wsf + WSF_PART;

    k1_classify<<<(BB * HWP / 4) / 256, 256, 0, stream>>>(preds, masks, L);
    k2_contract<<<dim3(NS2, BB), 256, 0, stream>>>(feats, L, partial, partialw);
    k3_finalize<<<KC, 256, 0, stream>>>(partial, partialw, out);
}

// Round 20
// 57.565 us; speedup vs baseline: 1.1070x; 1.1070x over previous
//
#include <hip/hip_runtime.h>

#define KC   21      // num classes
#define BB   8       // batch
#define CC   256     // feat channels
#define HWP  65536   // 256*256 output pixels per image
#define SRC  4096    // 64*64 source pixels
#define NS   128     // chunks: (y-row, half) -> 32 source cells each
#define PC   32      // source cells per chunk

typedef float f32x4 __attribute__((ext_vector_type(4)));

// d_ws layout: L = 524288 BYTES [0, 524288) | partialw f32 @ byte 524288 | partial f32
#define WSF_PARTW 131072                     // float index (byte 524288)
#define WSF_PART  (WSF_PARTW + BB*NS*KC)     // float index of partial

// ---- k1: per-pixel argmax + gt-match -> label map (EXACT R16, proven) -------
__global__ __launch_bounds__(256, 2)
void k1_classify(const float* __restrict__ preds,
                 const int*   __restrict__ masks,
                 unsigned char* __restrict__ L,
                 float* __restrict__ out)
{
    int tid = threadIdx.x;
    if (blockIdx.x == 0) {
        float4* o4 = reinterpret_cast<float4*>(out);
#pragma unroll
        for (int i = 0; i < (KC * CC / 4 + 255) / 256; ++i) {
            int j = tid + i * 256;
            if (j < KC * CC / 4) o4[j] = make_float4(0.f, 0.f, 0.f, 0.f);
        }
    }

    int idx = blockIdx.x * 256 + tid;            // over B*HWP/4 = 131072
    int b   = idx >> 14;
    int hw4 = (idx & 16383) << 2;

    const float* pb = preds + (size_t)b * KC * HWP + hw4;
    float va[4][KC];
#pragma unroll
    for (int k = 0; k < KC; ++k) {
        float4 t = *reinterpret_cast<const float4*>(pb + (size_t)k * HWP);
        va[0][k] = t.x; va[1][k] = t.y; va[2][k] = t.z; va[3][k] = t.w;
    }

    int4 mm = *reinterpret_cast<const int4*>(masks + b * HWP + hw4);
    int mk[4] = { mm.x, mm.y, mm.z, mm.w };

    uchar4 r;
    unsigned char* rp = reinterpret_cast<unsigned char*>(&r);
#pragma unroll
    for (int j = 0; j < 4; ++j) {
        float best = va[j][0];
        int   bi   = 0;
#pragma unroll
        for (int k = 1; k < KC; ++k) {
            if (va[j][k] > best) { best = va[j][k]; bi = k; }  // first-index ties
        }
        rp[j] = (mk[j] == bi) ? (unsigned char)bi : (unsigned char)255;
    }
    *reinterpret_cast<uchar4*>(L + (size_t)b * HWP + hw4) = r;
}

// ---- k2: R16 core + NONTEMPORAL streaming -----------------------------------
// R15 isolated-k2 counters: WRITE 52.6 MB/rep vs 22 logical (2.4x write
// amplification), FETCH = full feats re-fetch, 2.5 TB/s effective while k1
// sustains 6.9. Theory: read-once feats + write-once partial thrash L2
// (write-allocate + dirty eviction). Fix: NT loads for feats, NT stores for
// partial -> streams bypass L2; everything else byte-identical to R16.
__global__ __launch_bounds__(512, 8)
void k2_contract(const float* __restrict__ feats,      // [B][C][SRC]
                 const unsigned char* __restrict__ L,  // [B][256][256]
                 float* __restrict__ partial,          // [B][NS][K][C] f32
                 float* __restrict__ partialw)         // [B][NS][K]
{
    __shared__ float ws[KC * PC];     // 2.6 KB, LDS-atomic gather target
    __shared__ float scr[KC * CC];    // 21.5 KB psub-combine scratch
    int s = blockIdx.x, b = blockIdx.y;
    int tid = threadIdx.x;            // 0..511
    int y = s >> 1, x0c = (s & 1) * PC;
    int p0 = y * 64 + x0c;

    int cp   = tid & 255;             // channel
    int psub = tid >> 8;              // wave-uniform p-half
    int pw   = psub * 16;

    if (tid < KC * PC / 4)            // zero ws: 168 float4
        *reinterpret_cast<float4*>(ws + tid * 4) = make_float4(0.f, 0.f, 0.f, 0.f);

    // feats: own row segment straight to registers via NT loads (read-once)
    float f[16];
    {
        const f32x4* frow = reinterpret_cast<const f32x4*>(
            feats + (size_t)(b * CC + cp) * SRC + p0 + pw);
#pragma unroll
        for (int q = 0; q < 4; ++q) {
            f32x4 t = __builtin_nontemporal_load(frow + q);
            f[q * 4 + 0] = t.x; f[q * 4 + 1] = t.y;
            f[q * 4 + 2] = t.z; f[q * 4 + 3] = t.w;
        }
    }
    __syncthreads();                  // ws zeroed

    // gather labels over influence zone: rows [4y-2,4y+5] x cols [4x0c-2,+135]
    {
        int r = tid >> 6, cb = tid & 63;              // 8 rows x 64 threads
        int h = 4 * y - 2 + r;
        if ((unsigned)h < 256u) {
            float sy = h * 0.25f - 0.375f;
            int   yt = (int)floorf(sy);
            float wy = sy - (float)yt;
            int ya = yt < 0 ? 0 : yt;
            int yb = yt + 1 > 63 ? 63 : yt + 1;
            float wyy = ((ya == y) ? (1.f - wy) : 0.f) + ((yb == y) ? wy : 0.f);
            if (wyy != 0.f) {
                const unsigned char* Lrow = L + ((size_t)b << 16) + ((size_t)h << 8);
                int wb0 = 4 * x0c - 2;
#pragma unroll
                for (int j = 0; j < 3; ++j) {
                    int col = cb + j * 64;
                    int w = wb0 + col;
                    if (col < 136 && (unsigned)w < 256u) {
                        int k = Lrow[w];
                        if (k < KC) {
                            float sx = w * 0.25f - 0.375f;
                            int   xt = (int)floorf(sx);
                            float wx = sx - (float)xt;
                            int xa = xt < 0 ? 0 : xt;
                            int xb = xt + 1 > 63 ? 63 : xt + 1;
                            if (xa >= x0c && xa < x0c + PC)
                                atomicAdd(&ws[k * PC + xa - x0c], wyy * (1.f - wx));  // dyadic-exact
                            if (xb >= x0c && xb < x0c + PC)
                                atomicAdd(&ws[k * PC + xb - x0c], wyy * wx);
                        }
                    }
                }
            }
        }
    }
    __syncthreads();                  // ws final

    // exact per-chunk class-count contribution (rotated reads)
    float swcnt = 0.f;
    if (tid < KC) {
#pragma unroll
        for (int p = 0; p < PC; ++p) swcnt += ws[tid * PC + ((p + tid) & (PC - 1))];
    }

    float acc[KC];
#pragma unroll
    for (int k = 0; k < KC; ++k) {    // fully unrolled, static idx
        const float* wk = ws + k * PC + pw;
        float a0 = 0.f, a1 = 0.f, a2 = 0.f, a3 = 0.f;
#pragma unroll
        for (int q = 0; q < 4; ++q) {
            float4 w4 = *reinterpret_cast<const float4*>(wk + q * 4);  // uniform b128
            a0 += w4.x * f[q * 4 + 0];
            a1 += w4.y * f[q * 4 + 1];
            a2 += w4.z * f[q * 4 + 2];
            a3 += w4.w * f[q * 4 + 3];
        }
        acc[k] = (a0 + a1) + (a2 + a3);
    }

    // psub combine: psub1 parks in scr, psub0 adds and NT-stores (write-once)
    if (psub == 1) {
#pragma unroll
        for (int k = 0; k < KC; ++k) scr[k * CC + cp] = acc[k];
    }
    __syncthreads();
    if (psub == 0) {
        float* op = partial + ((size_t)(b * NS + s)) * KC * CC + cp;
#pragma unroll
        for (int k = 0; k < KC; ++k)
            __builtin_nontemporal_store(acc[k] + scr[k * CC + cp], op + (size_t)k * CC);
    }

    if (tid < KC)
        __builtin_nontemporal_store(swcnt, partialw + (size_t)(b * NS + s) * KC + tid);
}

// ---- k3: reduce chunks (NT reads), derive exact counts, normalize -----------
__global__ __launch_bounds__(256)
void k3_finalize(const float* __restrict__ partial,   // [B][NS][K][C]
                 const float* __restrict__ partialw,  // [B][NS][K]
                 float* __restrict__ out)             // [K][C], zeroed by k1
{
    int k = blockIdx.x, b = blockIdx.y;
    int tid = threadIdx.x;

    const float* base = partial + ((size_t)(b * NS) * KC + k) * CC + tid;
    float acc = 0.f;
#pragma unroll 8
    for (int s = 0; s < NS; ++s)
        acc += __builtin_nontemporal_load(base + (size_t)s * KC * CC);

    __shared__ float red[2];
    float v = 0.f;
    if (tid < NS) v = partialw[(size_t)(b * NS + tid) * KC + k];
#pragma unroll
    for (int off = 32; off; off >>= 1) v += __shfl_down(v, off);
    if (tid < NS && (tid & 63) == 0) red[tid >> 6] = v;
    __syncthreads();
    float cnt = red[0] + red[1];     // dyadic-exact pixel count

    atomicAdd(&out[k * CC + tid], acc / (8.f * (cnt + 1e-6f)));
}

extern "C" void kernel_launch(void* const* d_in, const int* in_sizes, int n_in,
                              void* d_out, int out_size, void* d_ws, size_t ws_size,
                              hipStream_t stream) {
    const float* feats = (const float*)d_in[0];   // [8,256,64,64]
    const float* preds = (const float*)d_in[1];   // [8,21,256,256]
    const int*   masks = (const int*)  d_in[2];   // [8,256,256]
    float* out = (float*)d_out;                   // [21,256]

    float* wsf = (float*)d_ws;
    unsigned char* L = (unsigned char*)d_ws;      // 524288 bytes, fully written by k1
    float* partialw = wsf + WSF_PARTW;            // byte 524288: disjoint from L
    float* partial  = wsf + WSF_PART;

    k1_classify<<<(BB * HWP / 4) / 256, 256, 0, stream>>>(preds, masks, L, out);
    k2_contract<<<dim3(NS, BB), 512, 0, stream>>>(feats, L, partial, partialw);
    k3_finalize<<<dim3(KC, BB), 256, 0, stream>>>(partial, partialw, out);
}

// Round 21
// 33.346 us; speedup vs baseline: 1.9109x; 1.7263x over previous
//
#include <hip/hip_runtime.h>

#define KC   21      // num classes
#define BB   8       // batch
#define CC   256     // feat channels
#define HWP  65536   // 256*256 output pixels per image
#define SRC  4096    // 64*64 source pixels
#define NS   64      // chunks: one full source row (64 p) each
#define PC   64      // p per chunk

// d_ws layout: L = 524288 BYTES [0, 524288) | partialw f32 @ byte 524288
// (8*64*21 = 10752 floats) | partial f32 @ float idx 141824 (11 MB). Disjoint.
#define WSF_PARTW 131072
#define WSF_PART  (WSF_PARTW + BB*NS*KC)     // 141824

// ---- k1: per-pixel argmax + gt-match -> label map (EXACT R16, proven) -------
__global__ __launch_bounds__(256, 2)
void k1_classify(const float* __restrict__ preds,
                 const int*   __restrict__ masks,
                 unsigned char* __restrict__ L,
                 float* __restrict__ out)
{
    int tid = threadIdx.x;
    if (blockIdx.x == 0) {
        float4* o4 = reinterpret_cast<float4*>(out);
#pragma unroll
        for (int i = 0; i < (KC * CC / 4 + 255) / 256; ++i) {
            int j = tid + i * 256;
            if (j < KC * CC / 4) o4[j] = make_float4(0.f, 0.f, 0.f, 0.f);
        }
    }

    int idx = blockIdx.x * 256 + tid;            // over B*HWP/4 = 131072
    int b   = idx >> 14;
    int hw4 = (idx & 16383) << 2;

    const float* pb = preds + (size_t)b * KC * HWP + hw4;
    float va[4][KC];
#pragma unroll
    for (int k = 0; k < KC; ++k) {
        float4 t = *reinterpret_cast<const float4*>(pb + (size_t)k * HWP);
        va[0][k] = t.x; va[1][k] = t.y; va[2][k] = t.z; va[3][k] = t.w;
    }

    int4 mm = *reinterpret_cast<const int4*>(masks + b * HWP + hw4);
    int mk[4] = { mm.x, mm.y, mm.z, mm.w };

    uchar4 r;
    unsigned char* rp = reinterpret_cast<unsigned char*>(&r);
#pragma unroll
    for (int j = 0; j < 4; ++j) {
        float best = va[j][0];
        int   bi   = 0;
#pragma unroll
        for (int k = 1; k < KC; ++k) {
            if (va[j][k] > best) { best = va[j][k]; bi = k; }  // first-index ties
        }
        rp[j] = (mk[j] == bi) ? (unsigned char)bi : (unsigned char)255;
    }
    *reinterpret_cast<uchar4*>(L + (size_t)b * HWP + hw4) = r;
}

// ---- k2: full-source-row blocks (64 p) -> partial halved to 11 MB -----------
// Grid (64,8) x 512 thr = 2 blocks/CU = 16 waves/CU (R13-proven occupancy).
// Gather zone: hi-res rows [4s-2, 4s+5] x ALL 256 cols -> xa/xb always in
// [0,64): no column clipping, fewer branches. LDS atomics dyadic-exact.
// partial round-trip cut 44 -> 22 MB vs R16 (the measured HBM-bound stream).
__global__ __launch_bounds__(512, 4)
void k2_contract(const float* __restrict__ feats,      // [B][C][SRC]
                 const unsigned char* __restrict__ L,  // [B][256][256]
                 float* __restrict__ partial,          // [B][NS][K][C] f32
                 float* __restrict__ partialw)         // [B][NS][K]
{
    __shared__ float ws[KC * PC];     // [21][64] = 5.25 KB gather target
    __shared__ float scr[KC * CC];    // 21.5 KB psub-combine scratch
    int s = blockIdx.x, b = blockIdx.y;   // s = source row y
    int tid = threadIdx.x;            // 0..511
    int p0 = s * PC;

    int cp   = tid & 255;             // channel
    int psub = tid >> 8;              // wave-uniform p-half (32 p each)
    int pw   = psub * 32;

    if (tid < KC * PC / 4)            // zero ws: 336 float4
        *reinterpret_cast<float4*>(ws + tid * 4) = make_float4(0.f, 0.f, 0.f, 0.f);

    // feats: own row segment straight to registers (proven R16 pattern)
    float f[32];
    {
        const float* frow = feats + (size_t)(b * CC + cp) * SRC + p0 + pw;
#pragma unroll
        for (int q = 0; q < 8; ++q) {
            float4 t = *reinterpret_cast<const float4*>(frow + q * 4);
            f[q * 4 + 0] = t.x; f[q * 4 + 1] = t.y;
            f[q * 4 + 2] = t.z; f[q * 4 + 3] = t.w;
        }
    }
    __syncthreads();                  // ws zeroed

    // gather labels: 8 hi-res rows x 256 cols (full width, no col clipping)
    {
        int r = tid >> 6, cb = tid & 63;              // 8 rows x 64 threads
        int h = 4 * s - 2 + r;
        if ((unsigned)h < 256u) {
            float sy = h * 0.25f - 0.375f;
            int   yt = (int)floorf(sy);
            float wy = sy - (float)yt;
            int ya = yt < 0 ? 0 : yt;
            int yb = yt + 1 > 63 ? 63 : yt + 1;
            float wyy = ((ya == s) ? (1.f - wy) : 0.f) + ((yb == s) ? wy : 0.f);
            if (wyy != 0.f) {
                const unsigned char* Lrow = L + ((size_t)b << 16) + ((size_t)h << 8);
#pragma unroll
                for (int j = 0; j < 4; ++j) {
                    int w = cb + j * 64;              // all 256 cols
                    int k = Lrow[w];
                    if (k < KC) {
                        float sx = w * 0.25f - 0.375f;
                        int   xt = (int)floorf(sx);
                        float wx = sx - (float)xt;
                        int xa = xt < 0 ? 0 : xt;
                        int xb = xt + 1 > 63 ? 63 : xt + 1;
                        atomicAdd(&ws[k * PC + xa], wyy * (1.f - wx));  // dyadic-exact
                        atomicAdd(&ws[k * PC + xb], wyy * wx);
                    }
                }
            }
        }
    }
    __syncthreads();                  // ws final

    // exact per-chunk class-count contribution (rotated reads)
    float swcnt = 0.f;
    if (tid < KC) {
#pragma unroll
        for (int p = 0; p < PC; ++p) swcnt += ws[tid * PC + ((p + tid * 3) & (PC - 1))];
    }

    float acc[KC];
#pragma unroll
    for (int k = 0; k < KC; ++k) {    // fully unrolled, static idx
        const float* wk = ws + k * PC + pw;
        float a0 = 0.f, a1 = 0.f, a2 = 0.f, a3 = 0.f;
#pragma unroll
        for (int q = 0; q < 8; ++q) {
            float4 w4 = *reinterpret_cast<const float4*>(wk + q * 4);  // uniform b128
            a0 += w4.x * f[q * 4 + 0];
            a1 += w4.y * f[q * 4 + 1];
            a2 += w4.z * f[q * 4 + 2];
            a3 += w4.w * f[q * 4 + 3];
        }
        acc[k] = (a0 + a1) + (a2 + a3);
    }

    // psub combine: psub1 parks in scr, psub0 adds and stores (coalesced 1KB/k)
    if (psub == 1) {
#pragma unroll
        for (int k = 0; k < KC; ++k) scr[k * CC + cp] = acc[k];
    }
    __syncthreads();
    if (psub == 0) {
        float* op = partial + ((size_t)(b * NS + s)) * KC * CC + cp;
#pragma unroll
        for (int k = 0; k < KC; ++k)
            op[(size_t)k * CC] = acc[k] + scr[k * CC + cp];
    }

    if (tid < KC)
        partialw[(size_t)(b * NS + s) * KC + tid] = swcnt;  // dyadic-exact
}

// ---- k3: reduce 64 chunks, derive exact counts, normalize -------------------
__global__ __launch_bounds__(256)
void k3_finalize(const float* __restrict__ partial,   // [B][NS][K][C]
                 const float* __restrict__ partialw,  // [B][NS][K]
                 float* __restrict__ out)             // [K][C], zeroed by k1
{
    int k = blockIdx.x, b = blockIdx.y;
    int tid = threadIdx.x;

    const float* base = partial + ((size_t)(b * NS) * KC + k) * CC + tid;
    float acc = 0.f;
#pragma unroll 8
    for (int s = 0; s < NS; ++s) acc += base[(size_t)s * KC * CC];

    __shared__ float red;
    if (tid < 64) {                   // single-wave reduce of 64 chunk counts
        float v = partialw[(size_t)(b * NS + tid) * KC + k];
#pragma unroll
        for (int off = 32; off; off >>= 1) v += __shfl_down(v, off);
        if (tid == 0) red = v;
    }
    __syncthreads();
    float cnt = red;                  // dyadic-exact pixel count

    atomicAdd(&out[k * CC + tid], acc / (8.f * (cnt + 1e-6f)));
}

extern "C" void kernel_launch(void* const* d_in, const int* in_sizes, int n_in,
                              void* d_out, int out_size, void* d_ws, size_t ws_size,
                              hipStream_t stream) {
    const float* feats = (const float*)d_in[0];   // [8,256,64,64]
    const float* preds = (const float*)d_in[1];   // [8,21,256,256]
    const int*   masks = (const int*)  d_in[2];   // [8,256,256]
    float* out = (float*)d_out;                   // [21,256]

    float* wsf = (float*)d_ws;
    unsigned char* L = (unsigned char*)d_ws;      // 524288 bytes, fully written by k1
    float* partialw = wsf + WSF_PARTW;            // byte 524288: disjoint from L
    float* partial  = wsf + WSF_PART;

    k1_classify<<<(BB * HWP / 4) / 256, 256, 0, stream>>>(preds, masks, L, out);
    k2_contract<<<dim3(NS, BB), 512, 0, stream>>>(feats, L, partial, partialw);
    k3_finalize<<<dim3(KC, BB), 256, 0, stream>>>(partial, partialw, out);
}